// Round 8
// baseline (568.818 us; speedup 1.0000x reference)
//
#include <hip/hip_runtime.h>
#include <stdint.h>

#define NQ 12
#define NL 5
#define NIT 15
#define AMPS 16
#define CPB (NIT * NQ)   // 180 fused gate matrices per batch element

// One 256-thread block (4 waves) per batch element, 16 amps/lane.
// Layout A: idx bits  b11,b10 = wv ; b9..b4 = lane ; b3..b0 = r
// Layout B: idx bits  b11,b10 = r3,r2 ; b9..b4 = lane ; b3,b2 = wv ; b1,b0 = r1,r0
// A bit-transpose (swap contents of bits 11,10 <-> 3,2) toggles A<->B once per
// iteration; the two wv wires are applied as REGISTER butterflies in the layout
// where they are register bits. Only 12/16 amps move: 6 b128 writes + 6 reads.
// Per-qubit fused U's commute within an iteration -> any order; CZ last
// (diagonal, layout-specific sign mask).
// Coef table precomputed to global d_ws by coef_kernel (wave-uniform loads in
// the main loop -> off the DS pipe). Fallback: per-block LDS table.
// Packed fp32 VOP3P: 4 instr/amp/gate. Plain one-arg __launch_bounds__ only
// (min-waves hints -> VGPR 64 -> state spills, R3/R4).

typedef float f2 __attribute__((ext_vector_type(2)));

static __device__ __forceinline__ float f_u(unsigned u) { return __uint_as_float(u); }
static __device__ __forceinline__ unsigned u_f(float f) { return __float_as_uint(f); }

// ---- packed complex primitives ----
#define PK_MUL_RR(acc, C, S) \
    asm("v_pk_mul_f32 %0, %1, %2 op_sel_hi:[0,1]" : "=v"(acc) : "v"(C), "v"(S))
#define PK_FMA_I(acc, C, S) \
    asm("v_pk_fma_f32 %0, %1, %2, %0 op_sel:[1,1,0] op_sel_hi:[1,0,1] neg_lo:[1,0,0]" \
        : "+v"(acc) : "v"(C), "v"(S))
#define PK_FMA_R(acc, C, S) \
    asm("v_pk_fma_f32 %0, %1, %2, %0 op_sel_hi:[0,1,1]" : "+v"(acc) : "v"(C), "v"(S))
#define PK_FMA_IC(acc, C, S) \
    asm("v_pk_fma_f32 %0, %1, %2, %0 op_sel:[1,1,0] op_sel_hi:[1,0,1] neg_hi:[1,0,0]" \
        : "+v"(acc) : "v"(C), "v"(S))
#define PK_FMA_RN(acc, C, S) \
    asm("v_pk_fma_f32 %0, %1, %2, %0 op_sel_hi:[0,1,1] neg_lo:[1,0,0] neg_hi:[1,0,0]" \
        : "+v"(acc) : "v"(C), "v"(S))

// DST = CA (.) S + CB (.) O
#define CPLX_AB(DST, CA, S, CB, O)                                    \
    { f2 t_;                                                          \
      PK_MUL_RR(t_, CA, S); PK_FMA_I(t_, CA, S);                      \
      PK_FMA_R (t_, CB, O); PK_FMA_I(t_, CB, O);                      \
      DST = t_; }

template <int CTRL>
static __device__ __forceinline__ float dpp_xor(float v) {
    int u = (int)__float_as_uint(v);
    return __uint_as_float((unsigned)__builtin_amdgcn_update_dpp(u, u, CTRL, 0xF, 0xF, false));
}
static __device__ __forceinline__ float swz_xor4(float v) {
    return f_u((unsigned)__builtin_amdgcn_ds_swizzle((int)u_f(v), 0x101F));
}

#define AB_GATE_PK(OPX)                                                 \
    _Pragma("unroll")                                                   \
    for (int r = 0; r < AMPS; ++r) {                                    \
        f2 o; o.x = OPX(s[r].x); o.y = OPX(s[r].y);                     \
        CPLX_AB(s[r], CA, s[r], CB, o)                                  \
    }

// Register-bit wire: s0' = a(.)s0 + b(.)s1 ; s1' = -conj(b)(.)s0 + conj(a)(.)s1
template <int ST>
static __device__ __forceinline__ void reg_gate_pk(f2 (&s)[AMPS], f2 CAg, f2 CBg) {
#pragma unroll
    for (int r0 = 0; r0 < AMPS; ++r0) {
        if (r0 & ST) continue;
        const int r1 = r0 | ST;
        const f2 s0 = s[r0], s1 = s[r1];
        f2 t0, t1;
        PK_MUL_RR(t0, CAg, s0); PK_FMA_I (t0, CAg, s0);
        PK_FMA_R (t0, CBg, s1); PK_FMA_I (t0, CBg, s1);
        PK_MUL_RR(t1, CAg, s1); PK_FMA_IC(t1, CAg, s1);
        PK_FMA_RN(t1, CBg, s0); PK_FMA_I (t1, CBg, s0);
        s[r0] = t0; s[r1] = t1;
    }
}

// ---- fused U = RZ*RY*RX coefficient math (shared host of both builders) ----
static __device__ __forceinline__ float4 build_coef(float alpha, float beta, float gamma) {
    float sa, ca, sb, cb, sg, cg;
    sincosf(0.5f * alpha, &sa, &ca);
    sincosf(0.5f * beta,  &sb, &cb);
    sincosf(0.5f * gamma, &sg, &cg);
    float cbca = cb * ca, sbsa = sb * sa, sbca = sb * ca, cbsa = cb * sa;
    float ar =  cg * cbca + sg * sbsa;
    float ai =  cg * sbsa - sg * cbca;
    float br = -(cg * sbca + sg * cbsa);
    float bi =  sg * sbca - cg * cbsa;
    return make_float4(ar, ai, br, bi);
}

__global__ __launch_bounds__(256) void coef_kernel(
    const float* __restrict__ x, const float* __restrict__ iscale,
    const float* __restrict__ w, float4* __restrict__ ctab, int total)
{
    int gid = blockIdx.x * 256 + threadIdx.x;
    if (gid >= total) return;
    int b  = gid / CPB;
    int t  = gid - b * CPB;
    int it = t / NQ;
    int q  = t - it * NQ;
    int blk = it - 3 * (it / 3);
    float f     = x[(size_t)b * (4 * NQ) + NQ + blk * NQ + q];
    float alpha = iscale[it * NQ + q] * f;
    ctab[gid] = build_coef(alpha, w[it * 2 * NQ + q], w[it * 2 * NQ + NQ + q]);
}

template <bool TAB>
__global__ __launch_bounds__(256) void qsim_kernel(
    const float* __restrict__ x,
    const float* __restrict__ iscale,
    const float* __restrict__ w,
    const float* __restrict__ oscale,
    const float4* __restrict__ ctab,
    float* __restrict__ out)
{
    const int tid  = threadIdx.x;
    const int lane = tid & 63;
    const int wv   = tid >> 6;
    const int b    = blockIdx.x;

    extern __shared__ float4 smem[];
    float4* buf  = smem;          // 12 slots x 2 q x 64 lanes = 24 KB transpose buffer
    float4* clds = smem + 1536;   // fallback coef table (180 entries), !TAB only

    // transpose buffer addressing: conflict-free (lane innermost, 16B stride)
#define TBUF(SLOT, Q) buf[((((SLOT) << 1) | (Q)) << 6) | lane]

    if constexpr (!TAB) {
        if (tid < CPB) {
            const int it  = tid / NQ;
            const int q   = tid - it * NQ;
            const int blk = it - 3 * (it / 3);
            float f     = x[(size_t)b * (4 * NQ) + NQ + blk * NQ + q];
            float alpha = iscale[it * NQ + q] * f;
            clds[tid] = build_coef(alpha, w[it * 2 * NQ + q], w[it * 2 * NQ + NQ + q]);
        }
        __syncthreads();
    }

    f2 s[AMPS];
#pragma unroll
    for (int r = 0; r < AMPS; ++r) { s[r].x = 0.f; s[r].y = 0.f; }
    if (tid == 0) s[0].x = 1.f;

    // CZ-ring sign masks for BOTH layouts
    unsigned czmA = 0, czmB = 0;
#pragma unroll
    for (int r = 0; r < AMPS; ++r) {
        unsigned ia = ((unsigned)wv << 10) | ((unsigned)lane << 4) | (unsigned)r;
        unsigned ib = (((unsigned)(r >> 3) & 1u) << 11) | (((unsigned)(r >> 2) & 1u) << 10)
                    | ((unsigned)lane << 4)
                    | (((unsigned)(wv >> 1) & 1u) << 3) | (((unsigned)wv & 1u) << 2)
                    | ((unsigned)r & 3u);
        unsigned pa = ((unsigned)__popc((ia & (ia >> 1)) & 0x7FFu) + ((ia & (ia >> 11)) & 1u)) & 1u;
        unsigned pb = ((unsigned)__popc((ib & (ib >> 1)) & 0x7FFu) + ((ib & (ib >> 11)) & 1u)) & 1u;
        czmA |= pa << r;
        czmB |= pb << r;
    }

    // lane-wire per-thread constants (bits 9..4 = wires 2..7 in BOTH layouts)
    const bool hb2 = (lane >> 5) & 1;
    const bool hb3 = (lane >> 4) & 1;
    const unsigned sb4 = (unsigned)((lane >> 3) & 1) << 31;
    const unsigned sb5 = (unsigned)((lane >> 2) & 1) << 31;
    const unsigned sb6 = (unsigned)((lane >> 1) & 1) << 31;
    const unsigned sb7 = (unsigned)(lane & 1) << 31;

    const float4* gtab = TAB ? (ctab + (size_t)b * CPB) : nullptr;

#pragma unroll 1
    for (int it = 0; it < NIT; ++it) {
        float4 c[NQ];
        if constexpr (TAB) {
#pragma unroll
            for (int q = 0; q < NQ; ++q) c[q] = gtab[it * NQ + q];
        } else {
#pragma unroll
            for (int q = 0; q < NQ; ++q) c[q] = clds[it * NQ + q];
        }
        const bool ev = (it & 1) == 0;   // enter layout A on even iters

        // ---- pre-transpose register wires ----
        // even (layout A): r3..r0 = wires 8,9,10,11 ; odd (layout B): r3,r2 = wires 0,1
        {
            const float4 c0 = ev ? c[8] : c[0];
            const float4 c1 = ev ? c[9] : c[1];
            { const f2 CA = { c0.x, c0.y }, CB = { c0.z, c0.w }; reg_gate_pk<8>(s, CA, CB); }
            { const f2 CA = { c1.x, c1.y }, CB = { c1.z, c1.w }; reg_gate_pk<4>(s, CA, CB); }
            { const f2 CA = { c[10].x, c[10].y }, CB = { c[10].z, c[10].w }; reg_gate_pk<2>(s, CA, CB); }
            { const f2 CA = { c[11].x, c[11].y }, CB = { c[11].z, c[11].w }; reg_gate_pk<1>(s, CA, CB); }
        }

        // ---- lane wires (qubits 2..7), identical in both layouts ----
        { // qubit 2: xor32 -> permlane32_swap
            const f2 CP = { hb2 ? -c[2].z : c[2].x, hb2 ?  c[2].w : c[2].y };
            const f2 CQ = { hb2 ?  c[2].x : c[2].z, hb2 ? -c[2].y : c[2].w };
#pragma unroll
            for (int r = 0; r < AMPS; ++r) {
                auto dx = __builtin_amdgcn_permlane32_swap(u_f(s[r].x), u_f(s[r].x), false, false);
                auto dy = __builtin_amdgcn_permlane32_swap(u_f(s[r].y), u_f(s[r].y), false, false);
                f2 na = { f_u(dx[0]), f_u(dy[0]) };
                f2 nb = { f_u(dx[1]), f_u(dy[1]) };
                CPLX_AB(s[r], CP, na, CQ, nb)
            }
        }
        { // qubit 3: xor16 -> permlane16_swap
            const f2 CP = { hb3 ? -c[3].z : c[3].x, hb3 ?  c[3].w : c[3].y };
            const f2 CQ = { hb3 ?  c[3].x : c[3].z, hb3 ? -c[3].y : c[3].w };
#pragma unroll
            for (int r = 0; r < AMPS; ++r) {
                auto dx = __builtin_amdgcn_permlane16_swap(u_f(s[r].x), u_f(s[r].x), false, false);
                auto dy = __builtin_amdgcn_permlane16_swap(u_f(s[r].y), u_f(s[r].y), false, false);
                f2 na = { f_u(dx[0]), f_u(dy[0]) };
                f2 nb = { f_u(dx[1]), f_u(dy[1]) };
                CPLX_AB(s[r], CP, na, CQ, nb)
            }
        }
        { // qubit 4: xor8 -> DPP row_ror:8
            const f2 CA = { c[4].x, f_u(u_f(c[4].y) ^ sb4) };
            const f2 CB = { f_u(u_f(c[4].z) ^ sb4), c[4].w };
            AB_GATE_PK(dpp_xor<0x128>)
        }
        { // qubit 5: xor4 -> ds_swizzle, batched to hide lgkm latency
            const f2 CA = { c[5].x, f_u(u_f(c[5].y) ^ sb5) };
            const f2 CB = { f_u(u_f(c[5].z) ^ sb5), c[5].w };
#pragma unroll
            for (int h = 0; h < 2; ++h) {
                float ox[8], oy[8];
#pragma unroll
                for (int r = 0; r < 8; ++r) {
                    ox[r] = swz_xor4(s[h*8 + r].x);
                    oy[r] = swz_xor4(s[h*8 + r].y);
                }
#pragma unroll
                for (int r = 0; r < 8; ++r) {
                    f2 o = { ox[r], oy[r] };
                    CPLX_AB(s[h*8 + r], CA, s[h*8 + r], CB, o)
                }
            }
        }
        { // qubit 6: xor2 -> DPP quad_perm [2,3,0,1]
            const f2 CA = { c[6].x, f_u(u_f(c[6].y) ^ sb6) };
            const f2 CB = { f_u(u_f(c[6].z) ^ sb6), c[6].w };
            AB_GATE_PK(dpp_xor<0x4E>)
        }
        { // qubit 7: xor1 -> DPP quad_perm [1,0,3,2]
            const f2 CA = { c[7].x, f_u(u_f(c[7].y) ^ sb7) };
            const f2 CB = { f_u(u_f(c[7].z) ^ sb7), c[7].w };
            AB_GATE_PK(dpp_xor<0xB1>)
        }

        // ---- bit-transpose: swap contents of bits (11,10) <-> (3,2) ----
        // thread wv sends its group g (amps r=4g..4g+3) to thread g (same lane),
        // landing in that thread's group wv. Own group (g==wv) stays in place.
        __syncthreads();   // prior buf readers done
#pragma unroll
        for (int g = 0; g < 4; ++g) {
            if (g == wv) continue;                       // wave-uniform branch
            const int slot = g * 3 + (wv < g ? wv : wv - 1);
            TBUF(slot, 0) = make_float4(s[4*g+0].x, s[4*g+0].y, s[4*g+1].x, s[4*g+1].y);
            TBUF(slot, 1) = make_float4(s[4*g+2].x, s[4*g+2].y, s[4*g+3].x, s[4*g+3].y);
        }
        __syncthreads();
#pragma unroll
        for (int h = 0; h < 4; ++h) {
            if (h == wv) continue;
            const int slot = wv * 3 + (h < wv ? h : h - 1);
            const float4 pa = TBUF(slot, 0);
            const float4 pb = TBUF(slot, 1);
            s[4*h+0] = f2{ pa.x, pa.y }; s[4*h+1] = f2{ pa.z, pa.w };
            s[4*h+2] = f2{ pb.x, pb.y }; s[4*h+3] = f2{ pb.z, pb.w };
        }

        // ---- post-transpose register wires ----
        // even (now layout B): r3,r2 = wires 0,1 ; odd (now layout A): wires 8,9
        {
            const float4 c0 = ev ? c[0] : c[8];
            const float4 c1 = ev ? c[1] : c[9];
            { const f2 CA = { c0.x, c0.y }, CB = { c0.z, c0.w }; reg_gate_pk<8>(s, CA, CB); }
            { const f2 CA = { c1.x, c1.y }, CB = { c1.z, c1.w }; reg_gate_pk<4>(s, CA, CB); }
        }

        // ---- CZ ring (diagonal +-1), mask per current layout ----
        const unsigned mcz = ev ? czmB : czmA;
#pragma unroll
        for (int r = 0; r < AMPS; ++r) {
            const unsigned sgn = ((mcz >> r) & 1u) << 31;
            s[r].x = f_u(u_f(s[r].x) ^ sgn);
            s[r].y = f_u(u_f(s[r].y) ^ sgn);
        }
    }

    // ---- expvals. Final layout: B (NIT odd; iter14 enters A, ends B).
    // wire0 = b11 = r3, wire1 = b10 = r2, wire2 = b9 = lane5, wire3 = b8 = lane4.
    float pg[4];
#pragma unroll
    for (int g = 0; g < 4; ++g) {
        float p = 0.f;
#pragma unroll
        for (int j = 0; j < 4; ++j)
            p = fmaf(s[4*g+j].x, s[4*g+j].x, fmaf(s[4*g+j].y, s[4*g+j].y, p));
        pg[g] = p;
    }
    const float ptot = (pg[0] + pg[1]) + (pg[2] + pg[3]);
    float v0 = (pg[0] + pg[1]) - (pg[2] + pg[3]);   // sign by r3
    float v1 = (pg[0] + pg[2]) - (pg[1] + pg[3]);   // sign by r2
    float v2 = hb2 ? -ptot : ptot;                  // lane5
    float v3 = hb3 ? -ptot : ptot;                  // lane4
#pragma unroll
    for (int m = 1; m <= 32; m <<= 1) {
        v0 += __shfl_xor(v0, m);
        v1 += __shfl_xor(v1, m);
        v2 += __shfl_xor(v2, m);
        v3 += __shfl_xor(v3, m);
    }

    __syncthreads();   // buf reuse for cross-wave reduction
    if (lane == 0) buf[wv] = make_float4(v0, v1, v2, v3);
    __syncthreads();
    if (tid == 0) {
        float4 a0 = buf[0], a1 = buf[1], a2 = buf[2], a3 = buf[3];
        float4 o;
        o.x = (a0.x + a1.x + a2.x + a3.x) * oscale[0];
        o.y = (a0.y + a1.y + a2.y + a3.y) * oscale[1];
        o.z = (a0.z + a1.z + a2.z + a3.z) * oscale[2];
        o.w = (a0.w + a1.w + a2.w + a3.w) * oscale[3];
        *reinterpret_cast<float4*>(out + (size_t)b * 4) = o;
    }
#undef TBUF
}

extern "C" void kernel_launch(void* const* d_in, const int* in_sizes, int n_in,
                              void* d_out, int out_size, void* d_ws, size_t ws_size,
                              hipStream_t stream) {
    const float* x      = (const float*)d_in[0];
    const float* iscale = (const float*)d_in[1];
    const float* w      = (const float*)d_in[2];
    const float* oscale = (const float*)d_in[3];
    float* out          = (float*)d_out;

    const int batch = in_sizes[0] / (4 * NQ);
    const size_t need = (size_t)batch * CPB * sizeof(float4);

    if (ws_size >= need) {
        const int total = batch * CPB;
        coef_kernel<<<(total + 255) / 256, 256, 0, stream>>>(x, iscale, w, (float4*)d_ws, total);
        qsim_kernel<true><<<batch, 256, 12 * 2 * 64 * sizeof(float4), stream>>>(
            x, iscale, w, oscale, (const float4*)d_ws, out);
    } else {
        qsim_kernel<false><<<batch, 256, (12 * 2 * 64 + CPB) * sizeof(float4), stream>>>(
            x, iscale, w, oscale, nullptr, out);
    }
}

// Round 9
// 568.411 us; speedup vs baseline: 1.0007x; 1.0007x over previous
//
#include <hip/hip_runtime.h>
#include <stdint.h>

#define NQ 12
#define NL 5
#define NIT 15
#define AMPS 16
#define CPB (NIT * NQ)   // 180 fused gate matrices per batch element

// One 256-thread block (4 waves) per batch element, 16 amps/lane.
// Layout A: idx bits  b11,b10 = wv ; b9..b4 = lane ; b3..b0 = r
// Layout B: idx bits  b11,b10 = r3,r2 ; b9..b4 = lane ; b3,b2 = wv ; b1,b0 = r1,r0
// Bit-transpose (swap contents of bits 11,10 <-> 3,2) toggles A<->B each
// iteration; wv wires are applied as REGISTER butterflies in the layout where
// they are register bits. Only 12/16 amps move: 6 b128 writes + 6 reads.
// Coef table precomputed to global d_ws; the main loop keeps a register
// DOUBLE-BUFFER of the 12 coef float4s, prefetched one iteration ahead (the
// ~3K-cycle body hides the HBM latency; also forces the allocator past the
// 64-VGPR/8-wave budget so pk chains can interleave. R8: VGPR 40 -> starved).
// Packed fp32 VOP3P: 4 instr/amp/gate (v_pk_* = 4 cyc/wave64 -> FLOP floor).
// Plain one-arg __launch_bounds__ only (min-waves hints mis-lower: VGPR 64,
// state spills, R3/R4).

typedef float f2 __attribute__((ext_vector_type(2)));

static __device__ __forceinline__ float f_u(unsigned u) { return __uint_as_float(u); }
static __device__ __forceinline__ unsigned u_f(float f) { return __float_as_uint(f); }

// ---- packed complex primitives ----
#define PK_MUL_RR(acc, C, S) \
    asm("v_pk_mul_f32 %0, %1, %2 op_sel_hi:[0,1]" : "=v"(acc) : "v"(C), "v"(S))
#define PK_FMA_I(acc, C, S) \
    asm("v_pk_fma_f32 %0, %1, %2, %0 op_sel:[1,1,0] op_sel_hi:[1,0,1] neg_lo:[1,0,0]" \
        : "+v"(acc) : "v"(C), "v"(S))
#define PK_FMA_R(acc, C, S) \
    asm("v_pk_fma_f32 %0, %1, %2, %0 op_sel_hi:[0,1,1]" : "+v"(acc) : "v"(C), "v"(S))
#define PK_FMA_IC(acc, C, S) \
    asm("v_pk_fma_f32 %0, %1, %2, %0 op_sel:[1,1,0] op_sel_hi:[1,0,1] neg_hi:[1,0,0]" \
        : "+v"(acc) : "v"(C), "v"(S))
#define PK_FMA_RN(acc, C, S) \
    asm("v_pk_fma_f32 %0, %1, %2, %0 op_sel_hi:[0,1,1] neg_lo:[1,0,0] neg_hi:[1,0,0]" \
        : "+v"(acc) : "v"(C), "v"(S))

// DST = CA (.) S + CB (.) O
#define CPLX_AB(DST, CA, S, CB, O)                                    \
    { f2 t_;                                                          \
      PK_MUL_RR(t_, CA, S); PK_FMA_I(t_, CA, S);                      \
      PK_FMA_R (t_, CB, O); PK_FMA_I(t_, CB, O);                      \
      DST = t_; }

template <int CTRL>
static __device__ __forceinline__ float dpp_xor(float v) {
    int u = (int)__float_as_uint(v);
    return __uint_as_float((unsigned)__builtin_amdgcn_update_dpp(u, u, CTRL, 0xF, 0xF, false));
}
static __device__ __forceinline__ float swz_xor4(float v) {
    return f_u((unsigned)__builtin_amdgcn_ds_swizzle((int)u_f(v), 0x101F));
}

#define AB_GATE_PK(OPX)                                                 \
    _Pragma("unroll")                                                   \
    for (int r = 0; r < AMPS; ++r) {                                    \
        f2 o; o.x = OPX(s[r].x); o.y = OPX(s[r].y);                     \
        CPLX_AB(s[r], CA, s[r], CB, o)                                  \
    }

// Register-bit wire: s0' = a(.)s0 + b(.)s1 ; s1' = -conj(b)(.)s0 + conj(a)(.)s1
template <int ST>
static __device__ __forceinline__ void reg_gate_pk(f2 (&s)[AMPS], f2 CAg, f2 CBg) {
#pragma unroll
    for (int r0 = 0; r0 < AMPS; ++r0) {
        if (r0 & ST) continue;
        const int r1 = r0 | ST;
        const f2 s0 = s[r0], s1 = s[r1];
        f2 t0, t1;
        PK_MUL_RR(t0, CAg, s0); PK_FMA_I (t0, CAg, s0);
        PK_FMA_R (t0, CBg, s1); PK_FMA_I (t0, CBg, s1);
        PK_MUL_RR(t1, CAg, s1); PK_FMA_IC(t1, CAg, s1);
        PK_FMA_RN(t1, CBg, s0); PK_FMA_I (t1, CBg, s0);
        s[r0] = t0; s[r1] = t1;
    }
}

// ---- fused U = RZ*RY*RX coefficient math ----
static __device__ __forceinline__ float4 build_coef(float alpha, float beta, float gamma) {
    float sa, ca, sb, cb, sg, cg;
    sincosf(0.5f * alpha, &sa, &ca);
    sincosf(0.5f * beta,  &sb, &cb);
    sincosf(0.5f * gamma, &sg, &cg);
    float cbca = cb * ca, sbsa = sb * sa, sbca = sb * ca, cbsa = cb * sa;
    float ar =  cg * cbca + sg * sbsa;
    float ai =  cg * sbsa - sg * cbca;
    float br = -(cg * sbca + sg * cbsa);
    float bi =  sg * sbca - cg * cbsa;
    return make_float4(ar, ai, br, bi);
}

__global__ __launch_bounds__(256) void coef_kernel(
    const float* __restrict__ x, const float* __restrict__ iscale,
    const float* __restrict__ w, float4* __restrict__ ctab, int total)
{
    int gid = blockIdx.x * 256 + threadIdx.x;
    if (gid >= total) return;
    int b  = gid / CPB;
    int t  = gid - b * CPB;
    int it = t / NQ;
    int q  = t - it * NQ;
    int blk = it - 3 * (it / 3);
    float f     = x[(size_t)b * (4 * NQ) + NQ + blk * NQ + q];
    float alpha = iscale[it * NQ + q] * f;
    ctab[gid] = build_coef(alpha, w[it * 2 * NQ + q], w[it * 2 * NQ + NQ + q]);
}

template <bool TAB>
__global__ __launch_bounds__(256) void qsim_kernel(
    const float* __restrict__ x,
    const float* __restrict__ iscale,
    const float* __restrict__ w,
    const float* __restrict__ oscale,
    const float4* __restrict__ ctab,
    float* __restrict__ out)
{
    const int tid  = threadIdx.x;
    const int lane = tid & 63;
    const int wv   = tid >> 6;
    const int b    = blockIdx.x;

    extern __shared__ float4 smem[];
    float4* buf  = smem;          // 12 slots x 2 q x 64 lanes = 24 KB transpose buffer
    float4* clds = smem + 1536;   // fallback coef table (180 entries), !TAB only

#define TBUF(SLOT, Q) buf[((((SLOT) << 1) | (Q)) << 6) | lane]

    if constexpr (!TAB) {
        if (tid < CPB) {
            const int it  = tid / NQ;
            const int q   = tid - it * NQ;
            const int blk = it - 3 * (it / 3);
            float f     = x[(size_t)b * (4 * NQ) + NQ + blk * NQ + q];
            float alpha = iscale[it * NQ + q] * f;
            clds[tid] = build_coef(alpha, w[it * 2 * NQ + q], w[it * 2 * NQ + NQ + q]);
        }
        __syncthreads();
    }

    f2 s[AMPS];
#pragma unroll
    for (int r = 0; r < AMPS; ++r) { s[r].x = 0.f; s[r].y = 0.f; }
    if (tid == 0) s[0].x = 1.f;

    // CZ-ring sign masks for BOTH layouts
    unsigned czmA = 0, czmB = 0;
#pragma unroll
    for (int r = 0; r < AMPS; ++r) {
        unsigned ia = ((unsigned)wv << 10) | ((unsigned)lane << 4) | (unsigned)r;
        unsigned ib = (((unsigned)(r >> 3) & 1u) << 11) | (((unsigned)(r >> 2) & 1u) << 10)
                    | ((unsigned)lane << 4)
                    | (((unsigned)(wv >> 1) & 1u) << 3) | (((unsigned)wv & 1u) << 2)
                    | ((unsigned)r & 3u);
        unsigned pa = ((unsigned)__popc((ia & (ia >> 1)) & 0x7FFu) + ((ia & (ia >> 11)) & 1u)) & 1u;
        unsigned pb = ((unsigned)__popc((ib & (ib >> 1)) & 0x7FFu) + ((ib & (ib >> 11)) & 1u)) & 1u;
        czmA |= pa << r;
        czmB |= pb << r;
    }

    // lane-wire per-thread constants (bits 9..4 = wires 2..7 in BOTH layouts)
    const bool hb2 = (lane >> 5) & 1;
    const bool hb3 = (lane >> 4) & 1;
    const unsigned sb4 = (unsigned)((lane >> 3) & 1) << 31;
    const unsigned sb5 = (unsigned)((lane >> 2) & 1) << 31;
    const unsigned sb6 = (unsigned)((lane >> 1) & 1) << 31;
    const unsigned sb7 = (unsigned)(lane & 1) << 31;

    const float4* gtab = TAB ? (ctab + (size_t)b * CPB) : nullptr;

    // ---- coef register double-buffer: c = current iter, cn = prefetched ----
    float4 c[NQ];
    if constexpr (TAB) {
#pragma unroll
        for (int q = 0; q < NQ; ++q) c[q] = gtab[q];
    } else {
#pragma unroll
        for (int q = 0; q < NQ; ++q) c[q] = clds[q];
    }

#pragma unroll 1
    for (int it = 0; it < NIT; ++it) {
        // prefetch next iteration's coefs (latency hidden by this body)
        float4 cn[NQ];
        if constexpr (TAB) {
            const float4* nxt = gtab + (it + 1 < NIT ? (it + 1) * NQ : it * NQ);
#pragma unroll
            for (int q = 0; q < NQ; ++q) cn[q] = nxt[q];
        } else {
            const float4* nxt = clds + (it + 1 < NIT ? (it + 1) * NQ : it * NQ);
#pragma unroll
            for (int q = 0; q < NQ; ++q) cn[q] = nxt[q];
        }

        const bool ev = (it & 1) == 0;   // enter layout A on even iters

        // ---- pre-transpose register wires ----
        // even (layout A): r3..r0 = wires 8,9,10,11 ; odd (layout B): r3,r2 = wires 0,1
        {
            const float4 c0 = ev ? c[8] : c[0];
            const float4 c1 = ev ? c[9] : c[1];
            { const f2 CA = { c0.x, c0.y }, CB = { c0.z, c0.w }; reg_gate_pk<8>(s, CA, CB); }
            { const f2 CA = { c1.x, c1.y }, CB = { c1.z, c1.w }; reg_gate_pk<4>(s, CA, CB); }
            { const f2 CA = { c[10].x, c[10].y }, CB = { c[10].z, c[10].w }; reg_gate_pk<2>(s, CA, CB); }
            { const f2 CA = { c[11].x, c[11].y }, CB = { c[11].z, c[11].w }; reg_gate_pk<1>(s, CA, CB); }
        }

        // ---- lane wires (qubits 2..7), identical in both layouts ----
        { // qubit 2: xor32 -> permlane32_swap
            const f2 CP = { hb2 ? -c[2].z : c[2].x, hb2 ?  c[2].w : c[2].y };
            const f2 CQ = { hb2 ?  c[2].x : c[2].z, hb2 ? -c[2].y : c[2].w };
#pragma unroll
            for (int r = 0; r < AMPS; ++r) {
                auto dx = __builtin_amdgcn_permlane32_swap(u_f(s[r].x), u_f(s[r].x), false, false);
                auto dy = __builtin_amdgcn_permlane32_swap(u_f(s[r].y), u_f(s[r].y), false, false);
                f2 na = { f_u(dx[0]), f_u(dy[0]) };
                f2 nb = { f_u(dx[1]), f_u(dy[1]) };
                CPLX_AB(s[r], CP, na, CQ, nb)
            }
        }
        { // qubit 3: xor16 -> permlane16_swap
            const f2 CP = { hb3 ? -c[3].z : c[3].x, hb3 ?  c[3].w : c[3].y };
            const f2 CQ = { hb3 ?  c[3].x : c[3].z, hb3 ? -c[3].y : c[3].w };
#pragma unroll
            for (int r = 0; r < AMPS; ++r) {
                auto dx = __builtin_amdgcn_permlane16_swap(u_f(s[r].x), u_f(s[r].x), false, false);
                auto dy = __builtin_amdgcn_permlane16_swap(u_f(s[r].y), u_f(s[r].y), false, false);
                f2 na = { f_u(dx[0]), f_u(dy[0]) };
                f2 nb = { f_u(dx[1]), f_u(dy[1]) };
                CPLX_AB(s[r], CP, na, CQ, nb)
            }
        }
        { // qubit 4: xor8 -> DPP row_ror:8
            const f2 CA = { c[4].x, f_u(u_f(c[4].y) ^ sb4) };
            const f2 CB = { f_u(u_f(c[4].z) ^ sb4), c[4].w };
            AB_GATE_PK(dpp_xor<0x128>)
        }
        { // qubit 5: xor4 -> ds_swizzle; issue ALL 32 gathers, then consume
            const f2 CA = { c[5].x, f_u(u_f(c[5].y) ^ sb5) };
            const f2 CB = { f_u(u_f(c[5].z) ^ sb5), c[5].w };
            float ox[AMPS], oy[AMPS];
#pragma unroll
            for (int r = 0; r < AMPS; ++r) {
                ox[r] = swz_xor4(s[r].x);
                oy[r] = swz_xor4(s[r].y);
            }
#pragma unroll
            for (int r = 0; r < AMPS; ++r) {
                f2 o = { ox[r], oy[r] };
                CPLX_AB(s[r], CA, s[r], CB, o)
            }
        }
        { // qubit 6: xor2 -> DPP quad_perm [2,3,0,1]
            const f2 CA = { c[6].x, f_u(u_f(c[6].y) ^ sb6) };
            const f2 CB = { f_u(u_f(c[6].z) ^ sb6), c[6].w };
            AB_GATE_PK(dpp_xor<0x4E>)
        }
        { // qubit 7: xor1 -> DPP quad_perm [1,0,3,2]
            const f2 CA = { c[7].x, f_u(u_f(c[7].y) ^ sb7) };
            const f2 CB = { f_u(u_f(c[7].z) ^ sb7), c[7].w };
            AB_GATE_PK(dpp_xor<0xB1>)
        }

        // ---- bit-transpose: swap contents of bits (11,10) <-> (3,2) ----
        __syncthreads();   // prior buf readers done
#pragma unroll
        for (int g = 0; g < 4; ++g) {
            if (g == wv) continue;                       // wave-uniform branch
            const int slot = g * 3 + (wv < g ? wv : wv - 1);
            TBUF(slot, 0) = make_float4(s[4*g+0].x, s[4*g+0].y, s[4*g+1].x, s[4*g+1].y);
            TBUF(slot, 1) = make_float4(s[4*g+2].x, s[4*g+2].y, s[4*g+3].x, s[4*g+3].y);
        }
        __syncthreads();
#pragma unroll
        for (int h = 0; h < 4; ++h) {
            if (h == wv) continue;
            const int slot = wv * 3 + (h < wv ? h : h - 1);
            const float4 pa = TBUF(slot, 0);
            const float4 pb = TBUF(slot, 1);
            s[4*h+0] = f2{ pa.x, pa.y }; s[4*h+1] = f2{ pa.z, pa.w };
            s[4*h+2] = f2{ pb.x, pb.y }; s[4*h+3] = f2{ pb.z, pb.w };
        }

        // ---- post-transpose register wires ----
        // even (now layout B): r3,r2 = wires 0,1 ; odd (now layout A): wires 8,9
        {
            const float4 c0 = ev ? c[0] : c[8];
            const float4 c1 = ev ? c[1] : c[9];
            { const f2 CA = { c0.x, c0.y }, CB = { c0.z, c0.w }; reg_gate_pk<8>(s, CA, CB); }
            { const f2 CA = { c1.x, c1.y }, CB = { c1.z, c1.w }; reg_gate_pk<4>(s, CA, CB); }
        }

        // ---- CZ ring (diagonal +-1), mask per current layout ----
        const unsigned mcz = ev ? czmB : czmA;
#pragma unroll
        for (int r = 0; r < AMPS; ++r) {
            const unsigned sgn = ((mcz >> r) & 1u) << 31;
            s[r].x = f_u(u_f(s[r].x) ^ sgn);
            s[r].y = f_u(u_f(s[r].y) ^ sgn);
        }

        // rotate double-buffer
#pragma unroll
        for (int q = 0; q < NQ; ++q) c[q] = cn[q];
    }

    // ---- expvals. Final layout: B (NIT odd).
    // wire0 = b11 = r3, wire1 = b10 = r2, wire2 = b9 = lane5, wire3 = b8 = lane4.
    float pg[4];
#pragma unroll
    for (int g = 0; g < 4; ++g) {
        float p = 0.f;
#pragma unroll
        for (int j = 0; j < 4; ++j)
            p = fmaf(s[4*g+j].x, s[4*g+j].x, fmaf(s[4*g+j].y, s[4*g+j].y, p));
        pg[g] = p;
    }
    const float ptot = (pg[0] + pg[1]) + (pg[2] + pg[3]);
    float v0 = (pg[0] + pg[1]) - (pg[2] + pg[3]);   // sign by r3
    float v1 = (pg[0] + pg[2]) - (pg[1] + pg[3]);   // sign by r2
    float v2 = hb2 ? -ptot : ptot;                  // lane5
    float v3 = hb3 ? -ptot : ptot;                  // lane4
#pragma unroll
    for (int m = 1; m <= 32; m <<= 1) {
        v0 += __shfl_xor(v0, m);
        v1 += __shfl_xor(v1, m);
        v2 += __shfl_xor(v2, m);
        v3 += __shfl_xor(v3, m);
    }

    __syncthreads();   // buf reuse for cross-wave reduction
    if (lane == 0) buf[wv] = make_float4(v0, v1, v2, v3);
    __syncthreads();
    if (tid == 0) {
        float4 a0 = buf[0], a1 = buf[1], a2 = buf[2], a3 = buf[3];
        float4 o;
        o.x = (a0.x + a1.x + a2.x + a3.x) * oscale[0];
        o.y = (a0.y + a1.y + a2.y + a3.y) * oscale[1];
        o.z = (a0.z + a1.z + a2.z + a3.z) * oscale[2];
        o.w = (a0.w + a1.w + a2.w + a3.w) * oscale[3];
        *reinterpret_cast<float4*>(out + (size_t)b * 4) = o;
    }
#undef TBUF
}

extern "C" void kernel_launch(void* const* d_in, const int* in_sizes, int n_in,
                              void* d_out, int out_size, void* d_ws, size_t ws_size,
                              hipStream_t stream) {
    const float* x      = (const float*)d_in[0];
    const float* iscale = (const float*)d_in[1];
    const float* w      = (const float*)d_in[2];
    const float* oscale = (const float*)d_in[3];
    float* out          = (float*)d_out;

    const int batch = in_sizes[0] / (4 * NQ);
    const size_t need = (size_t)batch * CPB * sizeof(float4);

    if (ws_size >= need) {
        const int total = batch * CPB;
        coef_kernel<<<(total + 255) / 256, 256, 0, stream>>>(x, iscale, w, (float4*)d_ws, total);
        qsim_kernel<true><<<batch, 256, 12 * 2 * 64 * sizeof(float4), stream>>>(
            x, iscale, w, oscale, (const float4*)d_ws, out);
    } else {
        qsim_kernel<false><<<batch, 256, (12 * 2 * 64 + CPB) * sizeof(float4), stream>>>(
            x, iscale, w, oscale, nullptr, out);
    }
}

// Round 10
// 513.582 us; speedup vs baseline: 1.1076x; 1.1068x over previous
//
#include <hip/hip_runtime.h>
#include <stdint.h>

#define NQ 12
#define NL 5
#define NIT 15
#define AMPS 16
#define CPB (NIT * NQ)   // 180 fused gate matrices

// One 256-thread block (4 waves) per batch element, 16 amps/lane.
// Layout A: idx bits  b11,b10 = wv ; b9..b4 = lane ; b3..b0 = r
// Layout B: idx bits  b11,b10 = r3,r2 ; b9..b4 = lane ; b3,b2 = wv ; b1,b0 = r1,r0
// Bit-transpose (swap contents of bits 11,10 <-> 3,2) toggles A<->B each
// iteration; wv wires are applied as REGISTER butterflies in the layout where
// they are register bits (wires 10,11 are r-bits in BOTH layouts).
// Coef table in LDS, built once per block (R8/R9's global table put 11.6 MB
// of cold-HBM s_load latency at each iteration head -> 537->568 regression).
// Iteration 0 uses a PRODUCT-STATE fast path: state is |0..0>, so the first
// 12 gates give amp(idx) = prod_q U_q[bit_q, 0] -- ~35 cmul/thread instead of
// a full gate pass + transpose + 2 barriers.
// Packed fp32 VOP3P: 4 instr/amp/gate. Plain one-arg __launch_bounds__ only
// (min-waves hints mis-lower: VGPR 64, state spills, R3/R4).

typedef float f2 __attribute__((ext_vector_type(2)));

static __device__ __forceinline__ float f_u(unsigned u) { return __uint_as_float(u); }
static __device__ __forceinline__ unsigned u_f(float f) { return __float_as_uint(f); }

// ---- packed complex primitives ----
#define PK_MUL_RR(acc, C, S) \
    asm("v_pk_mul_f32 %0, %1, %2 op_sel_hi:[0,1]" : "=v"(acc) : "v"(C), "v"(S))
#define PK_FMA_I(acc, C, S) \
    asm("v_pk_fma_f32 %0, %1, %2, %0 op_sel:[1,1,0] op_sel_hi:[1,0,1] neg_lo:[1,0,0]" \
        : "+v"(acc) : "v"(C), "v"(S))
#define PK_FMA_R(acc, C, S) \
    asm("v_pk_fma_f32 %0, %1, %2, %0 op_sel_hi:[0,1,1]" : "+v"(acc) : "v"(C), "v"(S))
#define PK_FMA_IC(acc, C, S) \
    asm("v_pk_fma_f32 %0, %1, %2, %0 op_sel:[1,1,0] op_sel_hi:[1,0,1] neg_hi:[1,0,0]" \
        : "+v"(acc) : "v"(C), "v"(S))
#define PK_FMA_RN(acc, C, S) \
    asm("v_pk_fma_f32 %0, %1, %2, %0 op_sel_hi:[0,1,1] neg_lo:[1,0,0] neg_hi:[1,0,0]" \
        : "+v"(acc) : "v"(C), "v"(S))

// DST = CA (x) CB  (complex product; DST must not alias CA/CB)
#define CMUL(DST, CA, CB) \
    { PK_MUL_RR(DST, CA, CB); PK_FMA_I(DST, CA, CB); }

// DST = CA (.) S + CB (.) O
#define CPLX_AB(DST, CA, S, CB, O)                                    \
    { f2 t_;                                                          \
      PK_MUL_RR(t_, CA, S); PK_FMA_I(t_, CA, S);                      \
      PK_FMA_R (t_, CB, O); PK_FMA_I(t_, CB, O);                      \
      DST = t_; }

template <int CTRL>
static __device__ __forceinline__ float dpp_xor(float v) {
    int u = (int)__float_as_uint(v);
    return __uint_as_float((unsigned)__builtin_amdgcn_update_dpp(u, u, CTRL, 0xF, 0xF, false));
}
static __device__ __forceinline__ float swz_xor4(float v) {
    return f_u((unsigned)__builtin_amdgcn_ds_swizzle((int)u_f(v), 0x101F));
}

#define AB_GATE_PK(OPX)                                                 \
    _Pragma("unroll")                                                   \
    for (int r = 0; r < AMPS; ++r) {                                    \
        f2 o; o.x = OPX(s[r].x); o.y = OPX(s[r].y);                     \
        CPLX_AB(s[r], CA, s[r], CB, o)                                  \
    }

// Register-bit wire: s0' = a(.)s0 + b(.)s1 ; s1' = -conj(b)(.)s0 + conj(a)(.)s1
template <int ST>
static __device__ __forceinline__ void reg_gate_pk(f2 (&s)[AMPS], f2 CAg, f2 CBg) {
#pragma unroll
    for (int r0 = 0; r0 < AMPS; ++r0) {
        if (r0 & ST) continue;
        const int r1 = r0 | ST;
        const f2 s0 = s[r0], s1 = s[r1];
        f2 t0, t1;
        PK_MUL_RR(t0, CAg, s0); PK_FMA_I (t0, CAg, s0);
        PK_FMA_R (t0, CBg, s1); PK_FMA_I (t0, CBg, s1);
        PK_MUL_RR(t1, CAg, s1); PK_FMA_IC(t1, CAg, s1);
        PK_FMA_RN(t1, CBg, s0); PK_FMA_I (t1, CBg, s0);
        s[r0] = t0; s[r1] = t1;
    }
}

// ---- fused U = RZ*RY*RX coefficient math ----
static __device__ __forceinline__ float4 build_coef(float alpha, float beta, float gamma) {
    float sa, ca, sb, cb, sg, cg;
    sincosf(0.5f * alpha, &sa, &ca);
    sincosf(0.5f * beta,  &sb, &cb);
    sincosf(0.5f * gamma, &sg, &cg);
    float cbca = cb * ca, sbsa = sb * sa, sbca = sb * ca, cbsa = cb * sa;
    float ar =  cg * cbca + sg * sbsa;
    float ai =  cg * sbsa - sg * cbca;
    float br = -(cg * sbca + sg * cbsa);
    float bi =  sg * sbca - cg * cbsa;
    return make_float4(ar, ai, br, bi);
}

__global__ __launch_bounds__(256) void qsim_kernel(
    const float* __restrict__ x,
    const float* __restrict__ iscale,
    const float* __restrict__ w,
    const float* __restrict__ oscale,
    float* __restrict__ out)
{
    const int tid  = threadIdx.x;
    const int lane = tid & 63;
    const int wv   = tid >> 6;
    const int b    = blockIdx.x;

    __shared__ float4 buf[1536];    // 24 KB transpose buffer
    __shared__ float4 clds[CPB];    // 2.88 KB coef table

#define TBUF(SLOT, Q) buf[((((SLOT) << 1) | (Q)) << 6) | lane]

    // ---- prologue: all 180 fused gate matrices into LDS ----
    if (tid < CPB) {
        const int it  = tid / NQ;
        const int q   = tid - it * NQ;
        const int blk = it - 3 * (it / 3);
        float f     = x[(size_t)b * (4 * NQ) + NQ + blk * NQ + q];
        float alpha = iscale[it * NQ + q] * f;
        clds[tid] = build_coef(alpha, w[it * 2 * NQ + q], w[it * 2 * NQ + NQ + q]);
    }

    // CZ-ring sign masks for BOTH layouts
    unsigned czmA = 0, czmB = 0;
#pragma unroll
    for (int r = 0; r < AMPS; ++r) {
        unsigned ia = ((unsigned)wv << 10) | ((unsigned)lane << 4) | (unsigned)r;
        unsigned ib = (((unsigned)(r >> 3) & 1u) << 11) | (((unsigned)(r >> 2) & 1u) << 10)
                    | ((unsigned)lane << 4)
                    | (((unsigned)(wv >> 1) & 1u) << 3) | (((unsigned)wv & 1u) << 2)
                    | ((unsigned)r & 3u);
        unsigned pa = ((unsigned)__popc((ia & (ia >> 1)) & 0x7FFu) + ((ia & (ia >> 11)) & 1u)) & 1u;
        unsigned pb = ((unsigned)__popc((ib & (ib >> 1)) & 0x7FFu) + ((ib & (ib >> 11)) & 1u)) & 1u;
        czmA |= pa << r;
        czmB |= pb << r;
    }

    // lane-wire per-thread constants (bits 9..4 = wires 2..7 in BOTH layouts)
    const bool hb2 = (lane >> 5) & 1;
    const bool hb3 = (lane >> 4) & 1;
    const unsigned sb4 = (unsigned)((lane >> 3) & 1) << 31;
    const unsigned sb5 = (unsigned)((lane >> 2) & 1) << 31;
    const unsigned sb6 = (unsigned)((lane >> 1) & 1) << 31;
    const unsigned sb7 = (unsigned)(lane & 1) << 31;

    __syncthreads();   // coef table ready

    f2 s[AMPS];

    // ================= iteration 0: product-state fast path =================
    // amp(idx) = prod_q U_q[bit_q, 0];  U[0,0] = (ar,ai), U[1,0] = (-br, bi).
    // Built directly in layout B; then CZ with czmB. Equivalent to running the
    // full it=0 gate pass + transpose (gates within an iteration commute).
    {
        float4 c[NQ];
#pragma unroll
        for (int q = 0; q < NQ; ++q) c[q] = clds[q];

        // thread-constant product: wires 2..7 (lane bits 5..0), 8,9 (wv bits)
        f2 tc;
        {
            const int b2 = (lane >> 5) & 1;
            tc = b2 ? f2{ -c[2].z, c[2].w } : f2{ c[2].x, c[2].y };
#pragma unroll
            for (int wq = 3; wq <= 7; ++wq) {
                const int bit = (lane >> (7 - wq)) & 1;
                const f2 uw = bit ? f2{ -c[wq].z, c[wq].w } : f2{ c[wq].x, c[wq].y };
                f2 t; CMUL(t, tc, uw); tc = t;
            }
            const int b8 = (wv >> 1) & 1;
            const f2 u8 = b8 ? f2{ -c[8].z, c[8].w } : f2{ c[8].x, c[8].y };
            { f2 t; CMUL(t, tc, u8); tc = t; }
            const int b9 = wv & 1;
            const f2 u9 = b9 ? f2{ -c[9].z, c[9].w } : f2{ c[9].x, c[9].y };
            { f2 t; CMUL(t, tc, u9); tc = t; }
        }

        // ph[j]: wires 0,1 by j=r>>2 (r3 -> wire0, r2 -> wire1), tc folded in
        // pl[k]: wires 10,11 by k=r&3 (r1 -> wire10, r0 -> wire11)
        f2 ph[4], pl[4];
        {
            const f2 a0 = { c[0].x, c[0].y }, a1 = { -c[0].z, c[0].w };
            const f2 b0 = { c[1].x, c[1].y }, b1 = { -c[1].z, c[1].w };
            CMUL(ph[0], a0, b0) CMUL(ph[1], a0, b1)
            CMUL(ph[2], a1, b0) CMUL(ph[3], a1, b1)
#pragma unroll
            for (int j = 0; j < 4; ++j) { f2 t; CMUL(t, tc, ph[j]); ph[j] = t; }
            const f2 g0 = { c[10].x, c[10].y }, g1 = { -c[10].z, c[10].w };
            const f2 h0 = { c[11].x, c[11].y }, h1 = { -c[11].z, c[11].w };
            CMUL(pl[0], g0, h0) CMUL(pl[1], g0, h1)
            CMUL(pl[2], g1, h0) CMUL(pl[3], g1, h1)
        }
#pragma unroll
        for (int r = 0; r < AMPS; ++r) CMUL(s[r], ph[r >> 2], pl[r & 3])

        // CZ ring in layout B
#pragma unroll
        for (int r = 0; r < AMPS; ++r) {
            const unsigned sgn = ((czmB >> r) & 1u) << 31;
            s[r].x = f_u(u_f(s[r].x) ^ sgn);
            s[r].y = f_u(u_f(s[r].y) ^ sgn);
        }
    }

    // ================= iterations 1..14 =================
#pragma unroll 2
    for (int it = 1; it < NIT; ++it) {
        float4 c[NQ];
#pragma unroll
        for (int q = 0; q < NQ; ++q) c[q] = clds[it * NQ + q];
        const bool ev = (it & 1) == 0;   // even iters enter layout A

        // ---- pre-transpose register wires ----
        // even (layout A): r3,r2 = wires 8,9 ; odd (layout B): r3,r2 = wires 0,1
        // wires 10,11 are r1,r0 in BOTH layouts
        {
            const float4 c0 = ev ? c[8] : c[0];
            const float4 c1 = ev ? c[9] : c[1];
            { const f2 CA = { c0.x, c0.y }, CB = { c0.z, c0.w }; reg_gate_pk<8>(s, CA, CB); }
            { const f2 CA = { c1.x, c1.y }, CB = { c1.z, c1.w }; reg_gate_pk<4>(s, CA, CB); }
            { const f2 CA = { c[10].x, c[10].y }, CB = { c[10].z, c[10].w }; reg_gate_pk<2>(s, CA, CB); }
            { const f2 CA = { c[11].x, c[11].y }, CB = { c[11].z, c[11].w }; reg_gate_pk<1>(s, CA, CB); }
        }

        // ---- lane wires (qubits 2..7), identical in both layouts ----
        { // qubit 2: xor32 -> permlane32_swap
            const f2 CP = { hb2 ? -c[2].z : c[2].x, hb2 ?  c[2].w : c[2].y };
            const f2 CQ = { hb2 ?  c[2].x : c[2].z, hb2 ? -c[2].y : c[2].w };
#pragma unroll
            for (int r = 0; r < AMPS; ++r) {
                auto dx = __builtin_amdgcn_permlane32_swap(u_f(s[r].x), u_f(s[r].x), false, false);
                auto dy = __builtin_amdgcn_permlane32_swap(u_f(s[r].y), u_f(s[r].y), false, false);
                f2 na = { f_u(dx[0]), f_u(dy[0]) };
                f2 nb = { f_u(dx[1]), f_u(dy[1]) };
                CPLX_AB(s[r], CP, na, CQ, nb)
            }
        }
        { // qubit 3: xor16 -> permlane16_swap
            const f2 CP = { hb3 ? -c[3].z : c[3].x, hb3 ?  c[3].w : c[3].y };
            const f2 CQ = { hb3 ?  c[3].x : c[3].z, hb3 ? -c[3].y : c[3].w };
#pragma unroll
            for (int r = 0; r < AMPS; ++r) {
                auto dx = __builtin_amdgcn_permlane16_swap(u_f(s[r].x), u_f(s[r].x), false, false);
                auto dy = __builtin_amdgcn_permlane16_swap(u_f(s[r].y), u_f(s[r].y), false, false);
                f2 na = { f_u(dx[0]), f_u(dy[0]) };
                f2 nb = { f_u(dx[1]), f_u(dy[1]) };
                CPLX_AB(s[r], CP, na, CQ, nb)
            }
        }
        { // qubit 4: xor8 -> DPP row_ror:8
            const f2 CA = { c[4].x, f_u(u_f(c[4].y) ^ sb4) };
            const f2 CB = { f_u(u_f(c[4].z) ^ sb4), c[4].w };
            AB_GATE_PK(dpp_xor<0x128>)
        }
        { // qubit 5: xor4 -> ds_swizzle; issue all gathers, then consume
            const f2 CA = { c[5].x, f_u(u_f(c[5].y) ^ sb5) };
            const f2 CB = { f_u(u_f(c[5].z) ^ sb5), c[5].w };
            float ox[AMPS], oy[AMPS];
#pragma unroll
            for (int r = 0; r < AMPS; ++r) {
                ox[r] = swz_xor4(s[r].x);
                oy[r] = swz_xor4(s[r].y);
            }
#pragma unroll
            for (int r = 0; r < AMPS; ++r) {
                f2 o = { ox[r], oy[r] };
                CPLX_AB(s[r], CA, s[r], CB, o)
            }
        }
        { // qubit 6: xor2 -> DPP quad_perm [2,3,0,1]
            const f2 CA = { c[6].x, f_u(u_f(c[6].y) ^ sb6) };
            const f2 CB = { f_u(u_f(c[6].z) ^ sb6), c[6].w };
            AB_GATE_PK(dpp_xor<0x4E>)
        }
        { // qubit 7: xor1 -> DPP quad_perm [1,0,3,2]
            const f2 CA = { c[7].x, f_u(u_f(c[7].y) ^ sb7) };
            const f2 CB = { f_u(u_f(c[7].z) ^ sb7), c[7].w };
            AB_GATE_PK(dpp_xor<0xB1>)
        }

        // ---- bit-transpose: swap contents of bits (11,10) <-> (3,2) ----
        __syncthreads();   // prior buf readers done
#pragma unroll
        for (int g = 0; g < 4; ++g) {
            if (g == wv) continue;                       // wave-uniform branch
            const int slot = g * 3 + (wv < g ? wv : wv - 1);
            TBUF(slot, 0) = make_float4(s[4*g+0].x, s[4*g+0].y, s[4*g+1].x, s[4*g+1].y);
            TBUF(slot, 1) = make_float4(s[4*g+2].x, s[4*g+2].y, s[4*g+3].x, s[4*g+3].y);
        }
        __syncthreads();
#pragma unroll
        for (int h = 0; h < 4; ++h) {
            if (h == wv) continue;
            const int slot = wv * 3 + (h < wv ? h : h - 1);
            const float4 pa = TBUF(slot, 0);
            const float4 pb = TBUF(slot, 1);
            s[4*h+0] = f2{ pa.x, pa.y }; s[4*h+1] = f2{ pa.z, pa.w };
            s[4*h+2] = f2{ pb.x, pb.y }; s[4*h+3] = f2{ pb.z, pb.w };
        }

        // ---- post-transpose register wires ----
        // even (now layout B): r3,r2 = wires 0,1 ; odd (now layout A): wires 8,9
        {
            const float4 c0 = ev ? c[0] : c[8];
            const float4 c1 = ev ? c[1] : c[9];
            { const f2 CA = { c0.x, c0.y }, CB = { c0.z, c0.w }; reg_gate_pk<8>(s, CA, CB); }
            { const f2 CA = { c1.x, c1.y }, CB = { c1.z, c1.w }; reg_gate_pk<4>(s, CA, CB); }
        }

        // ---- CZ ring (diagonal +-1), mask per current layout ----
        const unsigned mcz = ev ? czmB : czmA;
#pragma unroll
        for (int r = 0; r < AMPS; ++r) {
            const unsigned sgn = ((mcz >> r) & 1u) << 31;
            s[r].x = f_u(u_f(s[r].x) ^ sgn);
            s[r].y = f_u(u_f(s[r].y) ^ sgn);
        }
    }

    // ---- expvals. Final layout: B (it=14 enters A, exits B).
    // wire0 = b11 = r3, wire1 = b10 = r2, wire2 = b9 = lane5, wire3 = b8 = lane4.
    float pg[4];
#pragma unroll
    for (int g = 0; g < 4; ++g) {
        float p = 0.f;
#pragma unroll
        for (int j = 0; j < 4; ++j)
            p = fmaf(s[4*g+j].x, s[4*g+j].x, fmaf(s[4*g+j].y, s[4*g+j].y, p));
        pg[g] = p;
    }
    const float ptot = (pg[0] + pg[1]) + (pg[2] + pg[3]);
    float v0 = (pg[0] + pg[1]) - (pg[2] + pg[3]);   // sign by r3
    float v1 = (pg[0] + pg[2]) - (pg[1] + pg[3]);   // sign by r2
    float v2 = hb2 ? -ptot : ptot;                  // lane5
    float v3 = hb3 ? -ptot : ptot;                  // lane4
#pragma unroll
    for (int m = 1; m <= 32; m <<= 1) {
        v0 += __shfl_xor(v0, m);
        v1 += __shfl_xor(v1, m);
        v2 += __shfl_xor(v2, m);
        v3 += __shfl_xor(v3, m);
    }

    __syncthreads();   // buf reuse for cross-wave reduction
    if (lane == 0) buf[wv] = make_float4(v0, v1, v2, v3);
    __syncthreads();
    if (tid == 0) {
        float4 a0 = buf[0], a1 = buf[1], a2 = buf[2], a3 = buf[3];
        float4 o;
        o.x = (a0.x + a1.x + a2.x + a3.x) * oscale[0];
        o.y = (a0.y + a1.y + a2.y + a3.y) * oscale[1];
        o.z = (a0.z + a1.z + a2.z + a3.z) * oscale[2];
        o.w = (a0.w + a1.w + a2.w + a3.w) * oscale[3];
        *reinterpret_cast<float4*>(out + (size_t)b * 4) = o;
    }
#undef TBUF
}

extern "C" void kernel_launch(void* const* d_in, const int* in_sizes, int n_in,
                              void* d_out, int out_size, void* d_ws, size_t ws_size,
                              hipStream_t stream) {
    const float* x      = (const float*)d_in[0];
    const float* iscale = (const float*)d_in[1];
    const float* w      = (const float*)d_in[2];
    const float* oscale = (const float*)d_in[3];
    float* out          = (float*)d_out;

    const int batch = in_sizes[0] / (4 * NQ);
    qsim_kernel<<<batch, 256, 0, stream>>>(x, iscale, w, oscale, out);
}